// Round 4
// baseline (174.613 us; speedup 1.0000x reference)
//
#include <hip/hip_runtime.h>

// KAN conv (8x1x384x384 f32) -> out (8x1x384x384 f32)
// out[p] = rb + sum_{e in 5x5} sum_{f in 9} Wc[f][e] * F[f][p+e]
// F = (silu(x), bspline_0..7(x)); border phantoms precomputed into ws by kan_prep.

#define HW 384
#define NIMG 8
#define NPX (NIMG * HW * HW)

#define TW 64
#define TH 16
#define FROWS (TH + 4)        // 20
#define FCOLS (TW + 8)        // 72 floats/row, 18 float4-groups
#define NGRP 18
#define FPOS (FROWS * FCOLS)  // 1440

#define NBORD 1532            // border px per image: 2*384 + 2*382
#define WS_WC 0               // ws[0..224]   : Wc[9][5][5]
#define WS_CORR 1024          // ws[1024..]   : corr[NIMG*NBORD]

// extended knot grid g[i] = (i-3)*0.4 - 1.0 (bit-identical to jnp arange*0.4f-1)
__host__ __device__ constexpr float gkf(int i) { return (float)(i - 3) * 0.4f - 1.0f; }

// Cox-de Boor recursion, verbatim structure of the reference
__device__ __forceinline__ void kan_feats(float x, float f[9]) {
  float b[11];
#pragma unroll
  for (int i = 0; i < 11; ++i)
    b[i] = (x >= gkf(i) && x < gkf(i + 1)) ? 1.0f : 0.0f;
#pragma unroll
  for (int k = 1; k <= 3; ++k) {
#pragma unroll
    for (int i = 0; i < 11 - k; ++i) {
      float lc = (x - gkf(i)) * (1.0f / (gkf(i + k) - gkf(i)));
      float rc = (gkf(i + k + 1) - x) * (1.0f / (gkf(i + k + 1) - gkf(i + 1)));
      b[i] = lc * b[i] + rc * b[i + 1];
    }
  }
  float sg = __builtin_amdgcn_rcpf(1.0f + __expf(-x));
  f[0] = x * sg;  // silu
#pragma unroll
  for (int i = 0; i < 8; ++i) f[1 + i] = b[i];
}

// per-row group rotation: group g of row r stored at (g + ((r>>1)&3)) mod 18.
// rows {wr, wr+2, wr+4, wr+6} read by one wave get 4 distinct rotations ->
// distinct banks across tyi; txi/txi+8 aliasing stays 2-way.
__device__ __forceinline__ int swz_pos(int r, int c) {
  int g = (c >> 2) + ((r >> 1) & 3);
  if (g >= NGRP) g -= NGRP;
  return r * FCOLS + (g << 2) + (c & 3);
}

// ---------------- prep: weights collapse + border corrections, one kernel
// block 0: Wc -> ws[0..224]; blocks 1..48: border corr -> ws[1024+gid]
__global__ void kan_prep(const float* __restrict__ bw, const float* __restrict__ sw,
                         const float* __restrict__ ss, const float* __restrict__ rw,
                         const float* __restrict__ x, float* __restrict__ ws) {
  __shared__ float l_bw[144], l_ss[144], l_rw[144], l_sw[1152], l_h[729];
  const int tid = threadIdx.x;  // 256
  for (int i = tid; i < 144; i += 256) { l_bw[i] = bw[i]; l_ss[i] = ss[i]; l_rw[i] = rw[i]; }
  for (int i = tid; i < 1152; i += 256) l_sw[i] = sw[i];
  __syncthreads();
  // h[(d*9+k)*9+f] = sum_c rw[c,d] * (f==0 ? bw[c,k] : sw[c,k,f-1]*ss[c,k])
  for (int i = tid; i < 729; i += 256) {
    int f = i % 9, dk = i / 9, d = dk / 9, k = dk % 9;
    float acc = 0.f;
#pragma unroll
    for (int c = 0; c < 16; ++c) {
      float wfv = (f == 0) ? l_bw[c * 9 + k] : l_sw[(c * 9 + k) * 8 + (f - 1)] * l_ss[c * 9 + k];
      acc = fmaf(l_rw[c * 9 + d], wfv, acc);
    }
    l_h[i] = acc;
  }
  __syncthreads();

  if (blockIdx.x == 0) {
    if (tid < 225) {
      int f = tid / 25, e = tid % 25, ey = e / 5 - 2, ex = e % 5 - 2;
      float acc = 0.f;
#pragma unroll
      for (int d = 0; d < 9; ++d) {
        int dy = d / 3 - 1, dx = d % 3 - 1;
        int ky = ey - dy, kx = ex - dx;
        if (ky < -1 || ky > 1 || kx < -1 || kx > 1) continue;
        int k = (ky + 1) * 3 + (kx + 1);
        acc += l_h[(d * 9 + k) * 9 + f];
      }
      ws[WS_WC + tid] = acc;
    }
  } else {
    int gid = (blockIdx.x - 1) * 256 + tid;
    if (gid < NIMG * NBORD) {
      int img = gid / NBORD, rem = gid % NBORD;
      int pr, pc;
      if (rem < 384)       { pr = 0;              pc = rem; }
      else if (rem < 768)  { pr = 383;            pc = rem - 384; }
      else if (rem < 1150) { pr = rem - 768 + 1;  pc = 0; }
      else                 { pr = rem - 1150 + 1; pc = 383; }
      const float* xim = x + img * HW * HW;
      float corrv = 0.f;
#pragma unroll
      for (int dy = -1; dy <= 1; ++dy)
#pragma unroll
        for (int dx = -1; dx <= 1; ++dx) {
          int qr = pr + dy, qc = pc + dx;
          if (qr >= 0 && qr < HW && qc >= 0 && qc < HW) continue;  // only phantom q
          const int d = (dy + 1) * 3 + (dx + 1);
#pragma unroll
          for (int ky = -1; ky <= 1; ++ky)
#pragma unroll
            for (int kx = -1; kx <= 1; ++kx) {
              int sr = qr + ky, sc = qc + kx;
              float v = (sr >= 0 && sr < HW && sc >= 0 && sc < HW) ? xim[sr * HW + sc] : 0.0f;
              float fv[9];
              kan_feats(v, fv);
              const int k = (ky + 1) * 3 + (kx + 1);
              float t = 0.f;
#pragma unroll
              for (int ft = 0; ft < 9; ++ft) t = fmaf(l_h[(d * 9 + k) * 9 + ft], fv[ft], t);
              corrv += t;
            }
        }
      ws[WS_CORR + gid] = corrv;
    }
  }
}

// ---------------- main fused kernel
__launch_bounds__(128)
__global__ void kan_main(const float* __restrict__ x, const float* __restrict__ ws,
                         const float* __restrict__ rbp, float* __restrict__ out) {
  __shared__ __align__(16) float Fp[9][FPOS];  // 51840 B
  const float* Wc = ws + WS_WC;
  const float* corr = ws + WS_CORR;
  const int tx0 = blockIdx.x * TW, ty0 = blockIdx.y * TH, img = blockIdx.z;
  const float* xim = x + img * HW * HW;
  const int tid = threadIdx.y * 16 + threadIdx.x;

  // stage 1: F for halo'd tile (rows -2..17, cols -4..67), swizzled store
#pragma unroll
  for (int it = 0; it < 12; ++it) {
    int id = it * 128 + tid;
    if (id < FPOS) {
      int r = id / FCOLS, cl = id - r * FCOLS;
      int row = ty0 + r - 2, col = tx0 + cl - 4;
      float v = (row >= 0 && row < HW && col >= 0 && col < HW) ? xim[row * HW + col] : 0.0f;
      float f[9];
      kan_feats(v, f);
      const int pos = swz_pos(r, cl);
#pragma unroll
      for (int ft = 0; ft < 9; ++ft) Fp[ft][pos] = f[ft];
    }
  }
  __syncthreads();

  // stage 2: 25-tap stencil, micro-tile 4w x 2h; wr outer so swizzled addrs
  // are computed once and reused across the 9 feature planes (imm offsets)
  float acc[2][4] = {{0.f, 0.f, 0.f, 0.f}, {0.f, 0.f, 0.f, 0.f}};
  const int txi = threadIdx.x, tyi = threadIdx.y;
#pragma unroll
  for (int wr = 0; wr < 6; ++wr) {
    const int rr = 2 * tyi + wr;
    const int s = (rr >> 1) & 3;
    int ga = txi + s;     if (ga >= NGRP) ga -= NGRP;
    int gb = txi + 1 + s; if (gb >= NGRP) gb -= NGRP;
    int gc = txi + 2 + s; if (gc >= NGRP) gc -= NGRP;
    const int a0 = rr * FCOLS + (ga << 2);
    const int a1 = rr * FCOLS + (gb << 2);
    const int a2 = rr * FCOLS + (gc << 2);
#pragma unroll
    for (int f = 0; f < 9; ++f) {
      const float4 w0 = *(const float4*)&Fp[f][a0];
      const float4 w1 = *(const float4*)&Fp[f][a1];
      const float4 w2 = *(const float4*)&Fp[f][a2];
      const float w[12] = {w0.x, w0.y, w0.z, w0.w, w1.x, w1.y, w1.z, w1.w,
                           w2.x, w2.y, w2.z, w2.w};
#pragma unroll
      for (int r = 0; r < 2; ++r) {
        const int ey = wr - r;
        if (ey < 0 || ey > 4) continue;  // compile-time pruned
#pragma unroll
        for (int ex = 0; ex < 5; ++ex) {
          const float wt = Wc[f * 25 + ey * 5 + ex];  // wave-uniform -> s_load
#pragma unroll
          for (int c = 0; c < 4; ++c)
            acc[r][c] = fmaf(wt, w[c + ex + 2], acc[r][c]);
        }
      }
    }
  }

  // epilogue: bias, border correction, coalesced float4 store
  const float rb = rbp[0];
  const bool edgeblk = (tx0 == 0) | (tx0 == HW - TW) | (ty0 == 0) | (ty0 == HW - TH);
  float* oim = out + img * HW * HW;
#pragma unroll
  for (int r = 0; r < 2; ++r) {
    const int row = ty0 + 2 * tyi + r;
    const int col0 = tx0 + 4 * txi;
    float v[4];
#pragma unroll
    for (int c = 0; c < 4; ++c) v[c] = acc[r][c] + rb;
    if (edgeblk) {
#pragma unroll
      for (int c = 0; c < 4; ++c) {
        const int col = col0 + c;
        int bidx = -1;
        if (row == 0)            bidx = col;
        else if (row == HW - 1)  bidx = 384 + col;
        else if (col == 0)       bidx = 768 + row - 1;
        else if (col == HW - 1)  bidx = 1150 + row - 1;
        if (bidx >= 0) v[c] -= corr[img * NBORD + bidx];
      }
    }
    *(float4*)&oim[row * HW + col0] = make_float4(v[0], v[1], v[2], v[3]);
  }
}

// ---------------- ws-free correctness fallback (only if workspace is tiny)
__global__ void kan_direct(const float* __restrict__ x, const float* __restrict__ bw,
                           const float* __restrict__ sw, const float* __restrict__ ss,
                           const float* __restrict__ rw, const float* __restrict__ rbp,
                           float* __restrict__ out) {
  int idx = blockIdx.x * 256 + threadIdx.x;
  if (idx >= NPX) return;
  int img = idx / (HW * HW), rem = idx % (HW * HW);
  int pr = rem / HW, pc = rem % HW;
  const float* xim = x + img * HW * HW;
  float acc = rbp[0];
  for (int dy = -1; dy <= 1; ++dy)
    for (int dx = -1; dx <= 1; ++dx) {
      int qr = pr + dy, qc = pc + dx;
      if (qr < 0 || qr >= HW || qc < 0 || qc >= HW) continue;
      const int d = (dy + 1) * 3 + (dx + 1);
      for (int ky = -1; ky <= 1; ++ky)
        for (int kx = -1; kx <= 1; ++kx) {
          int sr = qr + ky, sc = qc + kx;
          float v = (sr >= 0 && sr < HW && sc >= 0 && sc < HW) ? xim[sr * HW + sc] : 0.0f;
          float f[9];
          kan_feats(v, f);
          const int k = (ky + 1) * 3 + (kx + 1);
          for (int c = 0; c < 16; ++c) {
            float spl = 0.f;
            for (int b = 0; b < 8; ++b) spl = fmaf(sw[(c * 9 + k) * 8 + b], f[1 + b], spl);
            acc = fmaf(rw[c * 9 + d], fmaf(bw[c * 9 + k], f[0], ss[c * 9 + k] * spl), acc);
          }
        }
    }
  out[idx] = acc;
}

extern "C" void kernel_launch(void* const* d_in, const int* in_sizes, int n_in,
                              void* d_out, int out_size, void* d_ws, size_t ws_size,
                              hipStream_t stream) {
  const float* x  = (const float*)d_in[0];
  const float* bw = (const float*)d_in[1];
  const float* sw = (const float*)d_in[2];
  const float* ss = (const float*)d_in[3];
  const float* rw = (const float*)d_in[4];
  const float* rb = (const float*)d_in[5];
  float* out = (float*)d_out;

  const size_t ws_need = (size_t)(WS_CORR + NIMG * NBORD) * sizeof(float);
  if (ws_size >= ws_need && d_ws != nullptr) {
    float* ws = (float*)d_ws;
    kan_prep<<<1 + (NIMG * NBORD + 255) / 256, 256, 0, stream>>>(bw, sw, ss, rw, x, ws);
    dim3 grid(HW / TW, HW / TH, NIMG), blk(16, 8);
    kan_main<<<grid, blk, 0, stream>>>(x, ws, rb, out);
  } else {
    kan_direct<<<(NPX + 255) / 256, 256, 0, stream>>>(x, bw, sw, ss, rw, rb, out);
  }
}

// Round 5
// 110.457 us; speedup vs baseline: 1.5808x; 1.5808x over previous
//
#include <hip/hip_runtime.h>

// KAN conv (8x1x384x384 f32) -> out (8x1x384x384 f32)
// out[p] = rb + sum_{e in 5x5} sum_{f in 9} Wc[f][e] * F[f][p+e]
// F = (silu(x), bspline_0..7(x)); border phantoms precomputed into ws by kan_prep.

#define HW 384
#define NIMG 8
#define NPX (NIMG * HW * HW)

#define TW 64
#define TH 16
#define FROWS (TH + 4)        // 20 halo rows (-2..17)
#define FCOLS 68              // halo cols -2..65 (left halo 2 -> 8-tap window float4-aligned)
#define NGRP 17               // 68/4 float4 groups per row
#define FPOS (FROWS * FCOLS)  // 1360 -> 5440 B/plane, 48.96 KB total (3 blocks/CU, 12 waves)

#define NBORD 1532            // border px per image: 2*384 + 2*382
#define WS_WC 0               // ws[0..224]   : Wc[9][5][5]
#define WS_CORR 1024          // ws[1024..]   : corr[NIMG*NBORD]

// Uniform-knot closed form of the reference's Cox-de Boor recursion.
// Knots g[i] = (i-3)*0.4-1; interval j = floor((x+2.2)*2.5); t in [0,1).
// Nonzero cubic bases on interval j are j-3..j with the cardinal weights
// w0=(1-t)^3/6, w1=(3t^3-6t^2+4)/6, w2=(-3t^3+3t^2+3t+1)/6, w3=t^3/6.
// Out-of-domain x (j<0 or j>10) -> all bases 0, matching the reference.
__device__ __forceinline__ void kan_feats(float x, float f[9]) {
  float sg = __builtin_amdgcn_rcpf(1.0f + __expf(-x));
  f[0] = x * sg;  // silu
  float u = (x + 2.2f) * 2.5f;
  float fj = floorf(u);
  int j = (int)fj;
  float t = u - fj;
  float omt = 1.0f - t;
  float t2 = t * t, t3 = t2 * t;
  float w0 = (1.0f / 6.0f) * omt * omt * omt;
  float w3 = (1.0f / 6.0f) * t3;
  float w1 = fmaf(0.5f, t3, fmaf(-1.0f, t2, 2.0f / 3.0f));
  float w2 = fmaf(-0.5f, t3, fmaf(0.5f, t2, fmaf(0.5f, t, 1.0f / 6.0f)));
#pragma unroll
  for (int i = 0; i < 8; ++i) {
    int d = i + 3 - j;  // basis i holds weight w[d] when 0<=d<=3
    float v = (d < 2) ? ((d == 0) ? w0 : w1) : ((d == 2) ? w2 : w3);
    f[1 + i] = ((unsigned)d <= 3u) ? v : 0.0f;
  }
}

// ---------------- prep: weights collapse + border corrections, one kernel
// block 0: Wc -> ws[0..224]; blocks 1..48: border corr -> ws[1024+gid]
__global__ void kan_prep(const float* __restrict__ bw, const float* __restrict__ sw,
                         const float* __restrict__ ss, const float* __restrict__ rw,
                         const float* __restrict__ x, float* __restrict__ ws) {
  __shared__ float l_bw[144], l_ss[144], l_rw[144], l_sw[1152], l_h[729];
  const int tid = threadIdx.x;  // 256
  for (int i = tid; i < 144; i += 256) { l_bw[i] = bw[i]; l_ss[i] = ss[i]; l_rw[i] = rw[i]; }
  for (int i = tid; i < 1152; i += 256) l_sw[i] = sw[i];
  __syncthreads();
  // h[(d*9+k)*9+f] = sum_c rw[c,d] * (f==0 ? bw[c,k] : sw[c,k,f-1]*ss[c,k])
  for (int i = tid; i < 729; i += 256) {
    int f = i % 9, dk = i / 9, d = dk / 9, k = dk % 9;
    float acc = 0.f;
#pragma unroll
    for (int c = 0; c < 16; ++c) {
      float wfv = (f == 0) ? l_bw[c * 9 + k] : l_sw[(c * 9 + k) * 8 + (f - 1)] * l_ss[c * 9 + k];
      acc = fmaf(l_rw[c * 9 + d], wfv, acc);
    }
    l_h[i] = acc;
  }
  __syncthreads();

  if (blockIdx.x == 0) {
    if (tid < 225) {
      int f = tid / 25, e = tid % 25, ey = e / 5 - 2, ex = e % 5 - 2;
      float acc = 0.f;
#pragma unroll
      for (int d = 0; d < 9; ++d) {
        int dy = d / 3 - 1, dx = d % 3 - 1;
        int ky = ey - dy, kx = ex - dx;
        if (ky < -1 || ky > 1 || kx < -1 || kx > 1) continue;
        int k = (ky + 1) * 3 + (kx + 1);
        acc += l_h[(d * 9 + k) * 9 + f];
      }
      ws[WS_WC + tid] = acc;
    }
  } else {
    int gid = (blockIdx.x - 1) * 256 + tid;
    if (gid < NIMG * NBORD) {
      int img = gid / NBORD, rem = gid % NBORD;
      int pr, pc;
      if (rem < 384)       { pr = 0;              pc = rem; }
      else if (rem < 768)  { pr = 383;            pc = rem - 384; }
      else if (rem < 1150) { pr = rem - 768 + 1;  pc = 0; }
      else                 { pr = rem - 1150 + 1; pc = 383; }
      const float* xim = x + img * HW * HW;
      float corrv = 0.f;
#pragma unroll
      for (int dy = -1; dy <= 1; ++dy)
#pragma unroll
        for (int dx = -1; dx <= 1; ++dx) {
          int qr = pr + dy, qc = pc + dx;
          if (qr >= 0 && qr < HW && qc >= 0 && qc < HW) continue;  // only phantom q
          const int d = (dy + 1) * 3 + (dx + 1);
#pragma unroll
          for (int ky = -1; ky <= 1; ++ky)
#pragma unroll
            for (int kx = -1; kx <= 1; ++kx) {
              int sr = qr + ky, sc = qc + kx;
              float v = (sr >= 0 && sr < HW && sc >= 0 && sc < HW) ? xim[sr * HW + sc] : 0.0f;
              float fv[9];
              kan_feats(v, fv);
              const int k = (ky + 1) * 3 + (kx + 1);
              float t = 0.f;
#pragma unroll
              for (int ft = 0; ft < 9; ++ft) t = fmaf(l_h[(d * 9 + k) * 9 + ft], fv[ft], t);
              corrv += t;
            }
        }
      ws[WS_CORR + gid] = corrv;
    }
  }
}

// ---------------- main fused kernel: 256 threads, micro-tile 4x1, 12 waves/CU
__launch_bounds__(256)
__global__ void kan_main(const float* __restrict__ x, const float* __restrict__ ws,
                         const float* __restrict__ rbp, float* __restrict__ out) {
  __shared__ __align__(16) float Fp[9][FPOS];  // 48960 B planar
  const float* Wc = ws + WS_WC;
  const float* corr = ws + WS_CORR;
  const int tx0 = blockIdx.x * TW, ty0 = blockIdx.y * TH, img = blockIdx.z;
  const float* xim = x + img * HW * HW;
  const int tid = threadIdx.y * 16 + threadIdx.x;

  // stage 1: F for halo'd tile (rows -2..17, cols -2..65), group-rotated store
#pragma unroll
  for (int it = 0; it < 6; ++it) {
    int id = it * 256 + tid;
    if (id < FPOS) {
      int r = id / FCOLS, cl = id - r * FCOLS;
      int row = ty0 + r - 2, col = tx0 + cl - 2;
      float v = (row >= 0 && row < HW && col >= 0 && col < HW) ? xim[row * HW + col] : 0.0f;
      float f[9];
      kan_feats(v, f);
      int g = (cl >> 2) + ((r >> 1) & 3);
      if (g >= NGRP) g -= NGRP;
      const int pos = r * FCOLS + (g << 2) + (cl & 3);
#pragma unroll
      for (int ft = 0; ft < 9; ++ft) Fp[ft][pos] = f[ft];
    }
  }
  __syncthreads();

  // stage 2: each thread owns 4 cols x 1 row; 8-tap window = 2 aligned b128/row.
  // Addresses hoisted once (10 ints); plane offset folds into ds_read immediate.
  const int txi = threadIdx.x, tyi = threadIdx.y;
  int adr[5][2];
#pragma unroll
  for (int ey = 0; ey < 5; ++ey) {
    const int rr = tyi + ey;
    const int s = (rr >> 1) & 3;
    int ga = txi + s;     if (ga >= NGRP) ga -= NGRP;
    int gb = txi + 1 + s; if (gb >= NGRP) gb -= NGRP;
    adr[ey][0] = rr * FCOLS + (ga << 2);
    adr[ey][1] = rr * FCOLS + (gb << 2);
  }

  float acc[4] = {0.f, 0.f, 0.f, 0.f};
#pragma unroll
  for (int f = 0; f < 9; ++f) {
#pragma unroll
    for (int ey = 0; ey < 5; ++ey) {
      const float4 wa = *(const float4*)&Fp[f][adr[ey][0]];
      const float4 wb = *(const float4*)&Fp[f][adr[ey][1]];
      const float w[8] = {wa.x, wa.y, wa.z, wa.w, wb.x, wb.y, wb.z, wb.w};
#pragma unroll
      for (int ex = 0; ex < 5; ++ex) {
        const float wt = Wc[f * 25 + ey * 5 + ex];  // wave-uniform -> s_load
#pragma unroll
        for (int c = 0; c < 4; ++c)
          acc[c] = fmaf(wt, w[c + ex], acc[c]);     // w[c+ex] = col 4txi+c+ex-2
      }
    }
  }

  // epilogue: bias, border correction, coalesced float4 store
  const float rb = rbp[0];
  const bool edgeblk = (tx0 == 0) | (tx0 == HW - TW) | (ty0 == 0) | (ty0 == HW - TH);
  float* oim = out + img * HW * HW;
  const int row = ty0 + tyi;
  const int col0 = tx0 + 4 * txi;
  float v[4];
#pragma unroll
  for (int c = 0; c < 4; ++c) v[c] = acc[c] + rb;
  if (edgeblk) {
#pragma unroll
    for (int c = 0; c < 4; ++c) {
      const int col = col0 + c;
      int bidx = -1;
      if (row == 0)            bidx = col;
      else if (row == HW - 1)  bidx = 384 + col;
      else if (col == 0)       bidx = 768 + row - 1;
      else if (col == HW - 1)  bidx = 1150 + row - 1;
      if (bidx >= 0) v[c] -= corr[img * NBORD + bidx];
    }
  }
  *(float4*)&oim[row * HW + col0] = make_float4(v[0], v[1], v[2], v[3]);
}

// ---------------- ws-free correctness fallback (only if workspace is tiny)
__global__ void kan_direct(const float* __restrict__ x, const float* __restrict__ bw,
                           const float* __restrict__ sw, const float* __restrict__ ss,
                           const float* __restrict__ rw, const float* __restrict__ rbp,
                           float* __restrict__ out) {
  int idx = blockIdx.x * 256 + threadIdx.x;
  if (idx >= NPX) return;
  int img = idx / (HW * HW), rem = idx % (HW * HW);
  int pr = rem / HW, pc = rem % HW;
  const float* xim = x + img * HW * HW;
  float acc = rbp[0];
  for (int dy = -1; dy <= 1; ++dy)
    for (int dx = -1; dx <= 1; ++dx) {
      int qr = pr + dy, qc = pc + dx;
      if (qr < 0 || qr >= HW || qc < 0 || qc >= HW) continue;
      const int d = (dy + 1) * 3 + (dx + 1);
      for (int ky = -1; ky <= 1; ++ky)
        for (int kx = -1; kx <= 1; ++kx) {
          int sr = qr + ky, sc = qc + kx;
          float v = (sr >= 0 && sr < HW && sc >= 0 && sc < HW) ? xim[sr * HW + sc] : 0.0f;
          float f[9];
          kan_feats(v, f);
          const int k = (ky + 1) * 3 + (kx + 1);
          for (int c = 0; c < 16; ++c) {
            float spl = 0.f;
            for (int b = 0; b < 8; ++b) spl = fmaf(sw[(c * 9 + k) * 8 + b], f[1 + b], spl);
            acc = fmaf(rw[c * 9 + d], fmaf(bw[c * 9 + k], f[0], ss[c * 9 + k] * spl), acc);
          }
        }
    }
  out[idx] = acc;
}

extern "C" void kernel_launch(void* const* d_in, const int* in_sizes, int n_in,
                              void* d_out, int out_size, void* d_ws, size_t ws_size,
                              hipStream_t stream) {
  const float* x  = (const float*)d_in[0];
  const float* bw = (const float*)d_in[1];
  const float* sw = (const float*)d_in[2];
  const float* ss = (const float*)d_in[3];
  const float* rw = (const float*)d_in[4];
  const float* rb = (const float*)d_in[5];
  float* out = (float*)d_out;

  const size_t ws_need = (size_t)(WS_CORR + NIMG * NBORD) * sizeof(float);
  if (ws_size >= ws_need && d_ws != nullptr) {
    float* ws = (float*)d_ws;
    kan_prep<<<1 + (NIMG * NBORD + 255) / 256, 256, 0, stream>>>(bw, sw, ss, rw, x, ws);
    dim3 grid(HW / TW, HW / TH, NIMG), blk(16, 16);
    kan_main<<<grid, blk, 0, stream>>>(x, ws, rb, out);
  } else {
    kan_direct<<<(NPX + 255) / 256, 256, 0, stream>>>(x, bw, sw, ss, rw, rb, out);
  }
}

// Round 6
// 103.718 us; speedup vs baseline: 1.6835x; 1.0650x over previous
//
#include <hip/hip_runtime.h>

// KAN conv (8x1x384x384 f32) -> out (8x1x384x384 f32)
// out[p] = rb + sum_{e in 5x5} sum_{f in 9} Wc[f][e] * F[f][p+e]
// F = (silu(x), bspline_0..7(x)); border phantoms precomputed into ws by kan_prep.
// F-planes in LDS: silu f32, spline bases f16 (range [0,0.67] -> err <= 2^-12).

#define HW 384
#define NIMG 8
#define NPX (NIMG * HW * HW)

#define TW 64
#define TH 16
#define FROWS (TH + 4)        // 20 halo rows (-2..17)
#define FCOLS 68              // logical halo cols -2..65 (8-tap window group-aligned)
#define FSTR 72               // padded row stride, elements (f32 words / f16 halves)
#define NGRP 18               // 72/4 vector-groups per row
#define FPOS (FROWS * FCOLS)  // 1360 logical positions
// LDS: f0 20*72*4 + 8 spline 20*72*2 = 5760 + 23040 = 28800 B -> 5 blocks/CU, 20 waves

#define NBORD 1532            // border px per image: 2*384 + 2*382
#define WS_WC 0               // ws[0..224]   : Wc[9][5][5]
#define WS_CORR 1024          // ws[1024..]   : corr[NIMG*NBORD]

typedef _Float16 half4v __attribute__((ext_vector_type(4)));

// Uniform-knot closed form of the reference's Cox-de Boor recursion.
// Knots g[i] = (i-3)*0.4-1; interval j = floor((x+2.2)*2.5); t in [0,1).
// Cardinal cubic weights w0..w3 on bases j-3..j; out-of-domain -> 0 (matches ref).
__device__ __forceinline__ void kan_feats(float x, float f[9]) {
  float sg = __builtin_amdgcn_rcpf(1.0f + __expf(-x));
  f[0] = x * sg;  // silu
  float u = (x + 2.2f) * 2.5f;
  float fj = floorf(u);
  int j = (int)fj;
  float t = u - fj;
  float omt = 1.0f - t;
  float t2 = t * t, t3 = t2 * t;
  float w0 = (1.0f / 6.0f) * omt * omt * omt;
  float w3 = (1.0f / 6.0f) * t3;
  float w1 = fmaf(0.5f, t3, fmaf(-1.0f, t2, 2.0f / 3.0f));
  float w2 = fmaf(-0.5f, t3, fmaf(0.5f, t2, fmaf(0.5f, t, 1.0f / 6.0f)));
#pragma unroll
  for (int i = 0; i < 8; ++i) {
    int d = i + 3 - j;  // basis i holds weight w[d] when 0<=d<=3
    float v = (d < 2) ? ((d == 0) ? w0 : w1) : ((d == 2) ? w2 : w3);
    f[1 + i] = ((unsigned)d <= 3u) ? v : 0.0f;
  }
}

// ---------------- prep: weights collapse + border corrections, one kernel
// block 0: Wc -> ws[0..224]; blocks 1..48: border corr -> ws[1024+gid]
__global__ void kan_prep(const float* __restrict__ bw, const float* __restrict__ sw,
                         const float* __restrict__ ss, const float* __restrict__ rw,
                         const float* __restrict__ x, float* __restrict__ ws) {
  __shared__ float l_bw[144], l_ss[144], l_rw[144], l_sw[1152], l_h[729];
  const int tid = threadIdx.x;  // 256
  for (int i = tid; i < 144; i += 256) { l_bw[i] = bw[i]; l_ss[i] = ss[i]; l_rw[i] = rw[i]; }
  for (int i = tid; i < 1152; i += 256) l_sw[i] = sw[i];
  __syncthreads();
  // h[(d*9+k)*9+f] = sum_c rw[c,d] * (f==0 ? bw[c,k] : sw[c,k,f-1]*ss[c,k])
  for (int i = tid; i < 729; i += 256) {
    int f = i % 9, dk = i / 9, d = dk / 9, k = dk % 9;
    float acc = 0.f;
#pragma unroll
    for (int c = 0; c < 16; ++c) {
      float wfv = (f == 0) ? l_bw[c * 9 + k] : l_sw[(c * 9 + k) * 8 + (f - 1)] * l_ss[c * 9 + k];
      acc = fmaf(l_rw[c * 9 + d], wfv, acc);
    }
    l_h[i] = acc;
  }
  __syncthreads();

  if (blockIdx.x == 0) {
    if (tid < 225) {
      int f = tid / 25, e = tid % 25, ey = e / 5 - 2, ex = e % 5 - 2;
      float acc = 0.f;
#pragma unroll
      for (int d = 0; d < 9; ++d) {
        int dy = d / 3 - 1, dx = d % 3 - 1;
        int ky = ey - dy, kx = ex - dx;
        if (ky < -1 || ky > 1 || kx < -1 || kx > 1) continue;
        int k = (ky + 1) * 3 + (kx + 1);
        acc += l_h[(d * 9 + k) * 9 + f];
      }
      ws[WS_WC + tid] = acc;
    }
  } else {
    int gid = (blockIdx.x - 1) * 256 + tid;
    if (gid < NIMG * NBORD) {
      int img = gid / NBORD, rem = gid % NBORD;
      int pr, pc;
      if (rem < 384)       { pr = 0;              pc = rem; }
      else if (rem < 768)  { pr = 383;            pc = rem - 384; }
      else if (rem < 1150) { pr = rem - 768 + 1;  pc = 0; }
      else                 { pr = rem - 1150 + 1; pc = 383; }
      const float* xim = x + img * HW * HW;
      float corrv = 0.f;
#pragma unroll
      for (int dy = -1; dy <= 1; ++dy)
#pragma unroll
        for (int dx = -1; dx <= 1; ++dx) {
          int qr = pr + dy, qc = pc + dx;
          if (qr >= 0 && qr < HW && qc >= 0 && qc < HW) continue;  // only phantom q
          const int d = (dy + 1) * 3 + (dx + 1);
#pragma unroll
          for (int ky = -1; ky <= 1; ++ky)
#pragma unroll
            for (int kx = -1; kx <= 1; ++kx) {
              int sr = qr + ky, sc = qc + kx;
              float v = (sr >= 0 && sr < HW && sc >= 0 && sc < HW) ? xim[sr * HW + sc] : 0.0f;
              float fv[9];
              kan_feats(v, fv);
              const int k = (ky + 1) * 3 + (kx + 1);
              float t = 0.f;
#pragma unroll
              for (int ft = 0; ft < 9; ++ft) t = fmaf(l_h[(d * 9 + k) * 9 + ft], fv[ft], t);
              corrv += t;
            }
        }
      ws[WS_CORR + gid] = corrv;
    }
  }
}

// ---------------- main fused kernel: 256 threads, micro-tile 4x1, 20 waves/CU
__launch_bounds__(256)
__global__ void kan_main(const float* __restrict__ x, const float* __restrict__ ws,
                         const float* __restrict__ rbp, float* __restrict__ out) {
  __shared__ __align__(16) float F0[FROWS * FSTR];           // silu plane, f32
  __shared__ __align__(16) _Float16 Fs[8][FROWS * FSTR];     // spline planes, f16
  const float* Wc = ws + WS_WC;
  const float* corr = ws + WS_CORR;
  const int tx0 = blockIdx.x * TW, ty0 = blockIdx.y * TH, img = blockIdx.z;
  const float* xim = x + img * HW * HW;
  const int tid = threadIdx.y * 16 + threadIdx.x;

  // stage 1: F for halo'd tile (rows -2..17, cols -2..65), group-rotated store
#pragma unroll
  for (int it = 0; it < 6; ++it) {
    int id = it * 256 + tid;
    if (id < FPOS) {
      int r = id / FCOLS, cl = id - r * FCOLS;
      int row = ty0 + r - 2, col = tx0 + cl - 2;
      float v = (row >= 0 && row < HW && col >= 0 && col < HW) ? xim[row * HW + col] : 0.0f;
      float f[9];
      kan_feats(v, f);
      int g = (cl >> 2) + ((r >> 1) & 3);
      if (g >= NGRP) g -= NGRP;
      const int pos = r * FSTR + (g << 2) + (cl & 3);
      F0[pos] = f[0];
#pragma unroll
      for (int ft = 0; ft < 8; ++ft) Fs[ft][pos] = (_Float16)f[1 + ft];
    }
  }
  __syncthreads();

  // stage 2: each thread owns 4 cols x 1 row; window = 2 vector-groups per row.
  const int txi = threadIdx.x, tyi = threadIdx.y;
  int adr[5][2];  // element index, shared by f32 and f16 planes
#pragma unroll
  for (int ey = 0; ey < 5; ++ey) {
    const int rr = tyi + ey;
    const int s = (rr >> 1) & 3;
    int ga = txi + s;     if (ga >= NGRP) ga -= NGRP;
    int gb = txi + 1 + s; if (gb >= NGRP) gb -= NGRP;
    adr[ey][0] = rr * FSTR + (ga << 2);
    adr[ey][1] = rr * FSTR + (gb << 2);
  }

  float acc[4] = {0.f, 0.f, 0.f, 0.f};
  // silu plane: f32, 2 x ds_read_b128 per ey
#pragma unroll
  for (int ey = 0; ey < 5; ++ey) {
    const float4 wa = *(const float4*)&F0[adr[ey][0]];
    const float4 wb = *(const float4*)&F0[adr[ey][1]];
    const float w[8] = {wa.x, wa.y, wa.z, wa.w, wb.x, wb.y, wb.z, wb.w};
#pragma unroll
    for (int ex = 0; ex < 5; ++ex) {
      const float wt = Wc[ey * 5 + ex];  // wave-uniform -> s_load
#pragma unroll
      for (int c = 0; c < 4; ++c)
        acc[c] = fmaf(wt, w[c + ex], acc[c]);
    }
  }
  // spline planes: f16, 2 x ds_read_b64 per (f,ey); f32 accumulate
#pragma unroll
  for (int f = 0; f < 8; ++f) {
#pragma unroll
    for (int ey = 0; ey < 5; ++ey) {
      const half4v ha = *(const half4v*)&Fs[f][adr[ey][0]];
      const half4v hb = *(const half4v*)&Fs[f][adr[ey][1]];
      const float w[8] = {(float)ha.x, (float)ha.y, (float)ha.z, (float)ha.w,
                          (float)hb.x, (float)hb.y, (float)hb.z, (float)hb.w};
#pragma unroll
      for (int ex = 0; ex < 5; ++ex) {
        const float wt = Wc[(1 + f) * 25 + ey * 5 + ex];  // wave-uniform -> s_load
#pragma unroll
        for (int c = 0; c < 4; ++c)
          acc[c] = fmaf(wt, w[c + ex], acc[c]);
      }
    }
  }

  // epilogue: bias, border correction, coalesced float4 store
  const float rb = rbp[0];
  const bool edgeblk = (tx0 == 0) | (tx0 == HW - TW) | (ty0 == 0) | (ty0 == HW - TH);
  float* oim = out + img * HW * HW;
  const int row = ty0 + tyi;
  const int col0 = tx0 + 4 * txi;
  float v[4];
#pragma unroll
  for (int c = 0; c < 4; ++c) v[c] = acc[c] + rb;
  if (edgeblk) {
#pragma unroll
    for (int c = 0; c < 4; ++c) {
      const int col = col0 + c;
      int bidx = -1;
      if (row == 0)            bidx = col;
      else if (row == HW - 1)  bidx = 384 + col;
      else if (col == 0)       bidx = 768 + row - 1;
      else if (col == HW - 1)  bidx = 1150 + row - 1;
      if (bidx >= 0) v[c] -= corr[img * NBORD + bidx];
    }
  }
  *(float4*)&oim[row * HW + col0] = make_float4(v[0], v[1], v[2], v[3]);
}

// ---------------- ws-free correctness fallback (only if workspace is tiny)
__global__ void kan_direct(const float* __restrict__ x, const float* __restrict__ bw,
                           const float* __restrict__ sw, const float* __restrict__ ss,
                           const float* __restrict__ rw, const float* __restrict__ rbp,
                           float* __restrict__ out) {
  int idx = blockIdx.x * 256 + threadIdx.x;
  if (idx >= NPX) return;
  int img = idx / (HW * HW), rem = idx % (HW * HW);
  int pr = rem / HW, pc = rem % HW;
  const float* xim = x + img * HW * HW;
  float acc = rbp[0];
  for (int dy = -1; dy <= 1; ++dy)
    for (int dx = -1; dx <= 1; ++dx) {
      int qr = pr + dy, qc = pc + dx;
      if (qr < 0 || qr >= HW || qc < 0 || qc >= HW) continue;
      const int d = (dy + 1) * 3 + (dx + 1);
      for (int ky = -1; ky <= 1; ++ky)
        for (int kx = -1; kx <= 1; ++kx) {
          int sr = qr + ky, sc = qc + kx;
          float v = (sr >= 0 && sr < HW && sc >= 0 && sc < HW) ? xim[sr * HW + sc] : 0.0f;
          float f[9];
          kan_feats(v, f);
          const int k = (ky + 1) * 3 + (kx + 1);
          for (int c = 0; c < 16; ++c) {
            float spl = 0.f;
            for (int b = 0; b < 8; ++b) spl = fmaf(sw[(c * 9 + k) * 8 + b], f[1 + b], spl);
            acc = fmaf(rw[c * 9 + d], fmaf(bw[c * 9 + k], f[0], ss[c * 9 + k] * spl), acc);
          }
        }
    }
  out[idx] = acc;
}

extern "C" void kernel_launch(void* const* d_in, const int* in_sizes, int n_in,
                              void* d_out, int out_size, void* d_ws, size_t ws_size,
                              hipStream_t stream) {
  const float* x  = (const float*)d_in[0];
  const float* bw = (const float*)d_in[1];
  const float* sw = (const float*)d_in[2];
  const float* ss = (const float*)d_in[3];
  const float* rw = (const float*)d_in[4];
  const float* rb = (const float*)d_in[5];
  float* out = (float*)d_out;

  const size_t ws_need = (size_t)(WS_CORR + NIMG * NBORD) * sizeof(float);
  if (ws_size >= ws_need && d_ws != nullptr) {
    float* ws = (float*)d_ws;
    kan_prep<<<1 + (NIMG * NBORD + 255) / 256, 256, 0, stream>>>(bw, sw, ss, rw, x, ws);
    dim3 grid(HW / TW, HW / TH, NIMG), blk(16, 16);
    kan_main<<<grid, blk, 0, stream>>>(x, ws, rb, out);
  } else {
    kan_direct<<<(NPX + 255) / 256, 256, 0, stream>>>(x, bw, sw, ss, rw, rb, out);
  }
}

// Round 8
// 102.781 us; speedup vs baseline: 1.6989x; 1.0091x over previous
//
#include <hip/hip_runtime.h>

// KAN conv (8x1x384x384 f32) -> out (8x1x384x384 f32)
// out[p] = rb + sum_{e in 5x5} sum_{f in 9} Wc[f][e] * F[f][p+e]
// F = (silu(x), bspline_0..7(x)); border phantoms precomputed into ws by kan_prep.
// LDS planes: silu f32; spline bases f16 packed in PAIRS (4 planes of half2/u32)
// -> stage-2 spline reads are ds_read_b128 (8 px x 2 features), 50 reads/thread total.

#define HW 384
#define NIMG 8
#define NPX (NIMG * HW * HW)

#define TW 64
#define TH 16
#define FROWS (TH + 4)        // 20 halo rows (-2..17)
#define FCOLS 68              // logical halo cols -2..65 (8-tap window group-aligned)
#define FSTR 72               // padded row stride, elements (f32 words / half2 words)
#define NGRP 18               // 72/4 vector-groups per row
#define FPOS (FROWS * FCOLS)  // 1360 logical positions
// LDS: f0 20*72*4 + 4 packed-pair planes 20*72*4 = 5760 + 23040 = 28800 B
// -> 5 blocks/CU, 20 waves/CU

#define NBORD 1532            // border px per image: 2*384 + 2*382
#define WS_WC 0               // ws[0..224]   : Wc[9][5][5]
#define WS_CORR 1024          // ws[1024..]   : corr[NIMG*NBORD]

typedef _Float16 half2v __attribute__((ext_vector_type(2)));
typedef _Float16 half8v __attribute__((ext_vector_type(8)));

// Uniform-knot closed form of the reference's Cox-de Boor recursion.
// Knots g[i] = (i-3)*0.4-1; interval j = floor((x+2.2)*2.5); t in [0,1).
// Cardinal cubic weights w0..w3 on bases j-3..j; out-of-domain -> 0 (matches ref).
__device__ __forceinline__ void kan_feats(float x, float f[9]) {
  float sg = __builtin_amdgcn_rcpf(1.0f + __expf(-x));
  f[0] = x * sg;  // silu
  float u = (x + 2.2f) * 2.5f;
  float fj = floorf(u);
  int j = (int)fj;
  float t = u - fj;
  float omt = 1.0f - t;
  float t2 = t * t, t3 = t2 * t;
  float w0 = (1.0f / 6.0f) * omt * omt * omt;
  float w3 = (1.0f / 6.0f) * t3;
  float w1 = fmaf(0.5f, t3, fmaf(-1.0f, t2, 2.0f / 3.0f));
  float w2 = fmaf(-0.5f, t3, fmaf(0.5f, t2, fmaf(0.5f, t, 1.0f / 6.0f)));
#pragma unroll
  for (int i = 0; i < 8; ++i) {
    int d = i + 3 - j;  // basis i holds weight w[d] when 0<=d<=3
    float v = (d < 2) ? ((d == 0) ? w0 : w1) : ((d == 2) ? w2 : w3);
    f[1 + i] = ((unsigned)d <= 3u) ? v : 0.0f;
  }
}

// ---------------- prep: weights collapse + border corrections, one kernel
// block 0: Wc -> ws[0..224]; blocks 1..48: border corr -> ws[1024+gid]
__global__ void kan_prep(const float* __restrict__ bw, const float* __restrict__ sw,
                         const float* __restrict__ ss, const float* __restrict__ rw,
                         const float* __restrict__ x, float* __restrict__ ws) {
  __shared__ float l_bw[144], l_ss[144], l_rw[144], l_sw[1152], l_h[729];
  const int tid = threadIdx.x;  // 256
  for (int i = tid; i < 144; i += 256) { l_bw[i] = bw[i]; l_ss[i] = ss[i]; l_rw[i] = rw[i]; }
  for (int i = tid; i < 1152; i += 256) l_sw[i] = sw[i];
  __syncthreads();
  // h[(d*9+k)*9+f] = sum_c rw[c,d] * (f==0 ? bw[c,k] : sw[c,k,f-1]*ss[c,k])
  for (int i = tid; i < 729; i += 256) {
    int f = i % 9, dk = i / 9, d = dk / 9, k = dk % 9;
    float acc = 0.f;
#pragma unroll
    for (int c = 0; c < 16; ++c) {
      float wfv = (f == 0) ? l_bw[c * 9 + k] : l_sw[(c * 9 + k) * 8 + (f - 1)] * l_ss[c * 9 + k];
      acc = fmaf(l_rw[c * 9 + d], wfv, acc);
    }
    l_h[i] = acc;
  }
  __syncthreads();

  if (blockIdx.x == 0) {
    if (tid < 225) {
      int f = tid / 25, e = tid % 25, ey = e / 5 - 2, ex = e % 5 - 2;
      float acc = 0.f;
#pragma unroll
      for (int d = 0; d < 9; ++d) {
        int dy = d / 3 - 1, dx = d % 3 - 1;
        int ky = ey - dy, kx = ex - dx;
        if (ky < -1 || ky > 1 || kx < -1 || kx > 1) continue;
        int k = (ky + 1) * 3 + (kx + 1);
        acc += l_h[(d * 9 + k) * 9 + f];
      }
      ws[WS_WC + tid] = acc;
    }
  } else {
    int gid = (blockIdx.x - 1) * 256 + tid;
    if (gid < NIMG * NBORD) {
      int img = gid / NBORD, rem = gid % NBORD;
      int pr, pc;
      if (rem < 384)       { pr = 0;              pc = rem; }
      else if (rem < 768)  { pr = 383;            pc = rem - 384; }
      else if (rem < 1150) { pr = rem - 768 + 1;  pc = 0; }
      else                 { pr = rem - 1150 + 1; pc = 383; }
      const float* xim = x + img * HW * HW;
      float corrv = 0.f;
#pragma unroll
      for (int dy = -1; dy <= 1; ++dy)
#pragma unroll
        for (int dx = -1; dx <= 1; ++dx) {
          int qr = pr + dy, qc = pc + dx;
          if (qr >= 0 && qr < HW && qc >= 0 && qc < HW) continue;  // only phantom q
          const int d = (dy + 1) * 3 + (dx + 1);
#pragma unroll
          for (int ky = -1; ky <= 1; ++ky)
#pragma unroll
            for (int kx = -1; kx <= 1; ++kx) {
              int sr = qr + ky, sc = qc + kx;
              float v = (sr >= 0 && sr < HW && sc >= 0 && sc < HW) ? xim[sr * HW + sc] : 0.0f;
              float fv[9];
              kan_feats(v, fv);
              const int k = (ky + 1) * 3 + (kx + 1);
              float t = 0.f;
#pragma unroll
              for (int ft = 0; ft < 9; ++ft) t = fmaf(l_h[(d * 9 + k) * 9 + ft], fv[ft], t);
              corrv += t;
            }
        }
      ws[WS_CORR + gid] = corrv;
    }
  }
}

// ---------------- main fused kernel: 256 threads, micro-tile 4x1, 20 waves/CU
__launch_bounds__(256)
__global__ void kan_main(const float* __restrict__ x, const float* __restrict__ ws,
                         const float* __restrict__ rbp, float* __restrict__ out) {
  __shared__ __align__(16) float F0[FROWS * FSTR];            // silu plane, f32
  __shared__ __align__(16) half2v Fs[4][FROWS * FSTR];        // spline pairs (2q, 2q+1)
  const float* Wc = ws + WS_WC;
  const float* corr = ws + WS_CORR;
  const int tx0 = blockIdx.x * TW, ty0 = blockIdx.y * TH, img = blockIdx.z;
  const float* xim = x + img * HW * HW;
  const int tid = threadIdx.y * 16 + threadIdx.x;

  // stage 1: F for halo'd tile (rows -2..17, cols -2..65), group-rotated store
#pragma unroll
  for (int it = 0; it < 6; ++it) {
    int id = it * 256 + tid;
    if (id < FPOS) {
      int r = id / FCOLS, cl = id - r * FCOLS;
      int row = ty0 + r - 2, col = tx0 + cl - 2;
      float v = (row >= 0 && row < HW && col >= 0 && col < HW) ? xim[row * HW + col] : 0.0f;
      float f[9];
      kan_feats(v, f);
      int g = (cl >> 2) + ((r >> 1) & 3);
      if (g >= NGRP) g -= NGRP;
      const int pos = r * FSTR + (g << 2) + (cl & 3);
      F0[pos] = f[0];
#pragma unroll
      for (int q = 0; q < 4; ++q) {
        half2v hp;
        hp.x = (_Float16)f[1 + 2 * q];
        hp.y = (_Float16)f[2 + 2 * q];
        Fs[q][pos] = hp;  // ds_write_b32
      }
    }
  }
  __syncthreads();

  // stage 2: each thread owns 4 cols x 1 row; window = 2 vector-groups per row.
  const int txi = threadIdx.x, tyi = threadIdx.y;
  int adr[5][2];  // element index (4B units), shared by f32 and half2 planes
#pragma unroll
  for (int ey = 0; ey < 5; ++ey) {
    const int rr = tyi + ey;
    const int s = (rr >> 1) & 3;
    int ga = txi + s;     if (ga >= NGRP) ga -= NGRP;
    int gb = txi + 1 + s; if (gb >= NGRP) gb -= NGRP;
    adr[ey][0] = rr * FSTR + (ga << 2);
    adr[ey][1] = rr * FSTR + (gb << 2);
  }

  float acc[4] = {0.f, 0.f, 0.f, 0.f};
  // silu plane: f32, 2 x ds_read_b128 per ey
#pragma unroll
  for (int ey = 0; ey < 5; ++ey) {
    const float4 wa = *(const float4*)&F0[adr[ey][0]];
    const float4 wb = *(const float4*)&F0[adr[ey][1]];
    const float w[8] = {wa.x, wa.y, wa.z, wa.w, wb.x, wb.y, wb.z, wb.w};
#pragma unroll
    for (int ex = 0; ex < 5; ++ex) {
      const float wt = Wc[ey * 5 + ex];  // wave-uniform -> s_load
#pragma unroll
      for (int c = 0; c < 4; ++c)
        acc[c] = fmaf(wt, w[c + ex], acc[c]);
    }
  }
  // spline pair-planes: 2 x ds_read_b128 per (q,ey) = 8 px x 2 features
#pragma unroll
  for (int q = 0; q < 4; ++q) {
    const float* Wl = Wc + (1 + 2 * q) * 25;
    const float* Wh = Wc + (2 + 2 * q) * 25;
#pragma unroll
    for (int ey = 0; ey < 5; ++ey) {
      const half8v a = *(const half8v*)&Fs[q][adr[ey][0]];
      const half8v b = *(const half8v*)&Fs[q][adr[ey][1]];
      // interleaved: a = {lo(p0),hi(p0),lo(p1),hi(p1),...}
      const float wl[8] = {(float)a[0], (float)a[2], (float)a[4], (float)a[6],
                           (float)b[0], (float)b[2], (float)b[4], (float)b[6]};
      const float wh[8] = {(float)a[1], (float)a[3], (float)a[5], (float)a[7],
                           (float)b[1], (float)b[3], (float)b[5], (float)b[7]};
#pragma unroll
      for (int ex = 0; ex < 5; ++ex) {
        const float wtl = Wl[ey * 5 + ex];
        const float wth = Wh[ey * 5 + ex];
#pragma unroll
        for (int c = 0; c < 4; ++c) {
          acc[c] = fmaf(wtl, wl[c + ex], acc[c]);
          acc[c] = fmaf(wth, wh[c + ex], acc[c]);
        }
      }
    }
  }

  // epilogue: bias, border correction, coalesced float4 store
  const float rb = rbp[0];
  const bool edgeblk = (tx0 == 0) | (tx0 == HW - TW) | (ty0 == 0) | (ty0 == HW - TH);
  float* oim = out + img * HW * HW;
  const int row = ty0 + tyi;
  const int col0 = tx0 + 4 * txi;
  float v[4];
#pragma unroll
  for (int c = 0; c < 4; ++c) v[c] = acc[c] + rb;
  if (edgeblk) {
#pragma unroll
    for (int c = 0; c < 4; ++c) {
      const int col = col0 + c;
      int bidx = -1;
      if (row == 0)            bidx = col;
      else if (row == HW - 1)  bidx = 384 + col;
      else if (col == 0)       bidx = 768 + row - 1;
      else if (col == HW - 1)  bidx = 1150 + row - 1;
      if (bidx >= 0) v[c] -= corr[img * NBORD + bidx];
    }
  }
  *(float4*)&oim[row * HW + col0] = make_float4(v[0], v[1], v[2], v[3]);
}

// ---------------- ws-free correctness fallback (only if workspace is tiny)
__global__ void kan_direct(const float* __restrict__ x, const float* __restrict__ bw,
                           const float* __restrict__ sw, const float* __restrict__ ss,
                           const float* __restrict__ rw, const float* __restrict__ rbp,
                           float* __restrict__ out) {
  int idx = blockIdx.x * 256 + threadIdx.x;
  if (idx >= NPX) return;
  int img = idx / (HW * HW), rem = idx % (HW * HW);
  int pr = rem / HW, pc = rem % HW;
  const float* xim = x + img * HW * HW;
  float acc = rbp[0];
  for (int dy = -1; dy <= 1; ++dy)
    for (int dx = -1; dx <= 1; ++dx) {
      int qr = pr + dy, qc = pc + dx;
      if (qr < 0 || qr >= HW || qc < 0 || qc >= HW) continue;
      const int d = (dy + 1) * 3 + (dx + 1);
      for (int ky = -1; ky <= 1; ++ky)
        for (int kx = -1; kx <= 1; ++kx) {
          int sr = qr + ky, sc = qc + kx;
          float v = (sr >= 0 && sr < HW && sc >= 0 && sc < HW) ? xim[sr * HW + sc] : 0.0f;
          float f[9];
          kan_feats(v, f);
          const int k = (ky + 1) * 3 + (kx + 1);
          for (int c = 0; c < 16; ++c) {
            float spl = 0.f;
            for (int b = 0; b < 8; ++b) spl = fmaf(sw[(c * 9 + k) * 8 + b], f[1 + b], spl);
            acc = fmaf(rw[c * 9 + d], fmaf(bw[c * 9 + k], f[0], ss[c * 9 + k] * spl), acc);
          }
        }
    }
  out[idx] = acc;
}

extern "C" void kernel_launch(void* const* d_in, const int* in_sizes, int n_in,
                              void* d_out, int out_size, void* d_ws, size_t ws_size,
                              hipStream_t stream) {
  const float* x  = (const float*)d_in[0];
  const float* bw = (const float*)d_in[1];
  const float* sw = (const float*)d_in[2];
  const float* ss = (const float*)d_in[3];
  const float* rw = (const float*)d_in[4];
  const float* rb = (const float*)d_in[5];
  float* out = (float*)d_out;

  const size_t ws_need = (size_t)(WS_CORR + NIMG * NBORD) * sizeof(float);
  if (ws_size >= ws_need && d_ws != nullptr) {
    float* ws = (float*)d_ws;
    kan_prep<<<1 + (NIMG * NBORD + 255) / 256, 256, 0, stream>>>(bw, sw, ss, rw, x, ws);
    dim3 grid(HW / TW, HW / TH, NIMG), blk(16, 16);
    kan_main<<<grid, blk, 0, stream>>>(x, ws, rb, out);
  } else {
    kan_direct<<<(NPX + 255) / 256, 256, 0, stream>>>(x, bw, sw, ss, rw, rb, out);
  }
}